// Round 1
// baseline (9903.403 us; speedup 1.0000x reference)
//
#include <hip/hip_runtime.h>

// Graph-attention sequential sweep, executed as dataflow over the dependency DAG.
// Node i depends only on out-rows g[j] for j in neighbors[i], j<i, k<deg[i].
// Workers grab node ids IN ORDER via atomic counter (deadlock-free: smallest
// unfinished id is always held by a resident wave whose deps are finished).

constexpr int NN = 50000;
constexpr int D  = 512;
constexpr int K  = 32;
constexpr int D4 = D / 4; // 128 float4 per row

__global__ __launch_bounds__(256) void precomp_kernel(
    const float* __restrict__ feats,
    const float* __restrict__ wq_w, const float* __restrict__ wq_b,
    const float* __restrict__ wk_w, const float* __restrict__ wk_b,
    float* __restrict__ ei, float* __restrict__ ej_orig)
{
    int gw   = (int)((blockIdx.x * blockDim.x + threadIdx.x) >> 6); // global wave id
    int lane = threadIdx.x & 63;
    if (gw >= NN) return;
    const float4* row = (const float4*)feats + (size_t)gw * D4;
    const float4* q4  = (const float4*)wq_w;
    const float4* k4  = (const float4*)wk_w;
    float dq = 0.f, dk = 0.f;
#pragma unroll
    for (int c = 0; c < 2; ++c) {
        float4 v  = row[lane + 64 * c];
        float4 q  = q4[lane + 64 * c];
        float4 kk = k4[lane + 64 * c];
        dq += v.x * q.x + v.y * q.y + v.z * q.z + v.w * q.w;
        dk += v.x * kk.x + v.y * kk.y + v.z * kk.z + v.w * kk.w;
    }
#pragma unroll
    for (int off = 32; off > 0; off >>= 1) {
        dq += __shfl_down(dq, off, 64);
        dk += __shfl_down(dk, off, 64);
    }
    if (lane == 0) {
        ei[gw]      = dq + wq_b[0];
        ej_orig[gw] = dk + wk_b[0];
    }
}

__global__ __launch_bounds__(256) void attn_dataflow(
    const float* __restrict__ feats,
    const float* __restrict__ wk_w, const float* __restrict__ wk_b,
    const int* __restrict__ neighbors, const int* __restrict__ deg,
    const float* __restrict__ ei_arr, const float* __restrict__ ej_orig,
    float* ej_new, int* flags, int* counter,
    float* out)
{
    const int lane = threadIdx.x & 63;
    const float4* f4  = (const float4*)feats;
    const float4* o4r = (const float4*)out;
    const float4* wk4 = (const float4*)wk_w;
    const float   wkb = wk_b[0];

    for (;;) {
        int id = 0;
        if (lane == 0) id = atomicAdd(counter, 1);
        id = __shfl(id, 0, 64);
        if (id >= NN) return;

        const int d = deg[id];
        int nbr = 0;
        if (lane < K) nbr = neighbors[(size_t)id * K + lane];
        const bool valid = lane < d;                // lanes >=32 never valid (d<=32)
        const bool isdep = valid && (nbr < id);

        // Wait for updated-neighbor rows. Agent-scope acquire: sc1 load bypasses
        // the (non-cross-coherent) XCD L2 so we always observe the producer's
        // flag, and the acquire orders/invalidates before the data reads below.
        if (isdep) {
            while (__hip_atomic_load(&flags[nbr], __ATOMIC_ACQUIRE,
                                     __HIP_MEMORY_SCOPE_AGENT) == 0) {
                __builtin_amdgcn_s_sleep(2);
            }
        }

        float4 acc0 = {0.f, 0.f, 0.f, 0.f};
        float4 acc1 = {0.f, 0.f, 0.f, 0.f};

        if (d > 0) {
            float ej = 0.f;
            if (valid) ej = isdep ? ej_new[nbr] : ej_orig[nbr];
            const float eii = ei_arr[id];
            float eij = valid ? eii * ej : -3.0e38f;
            float m = eij;
#pragma unroll
            for (int off = 32; off > 0; off >>= 1)
                m = fmaxf(m, __shfl_xor(m, off, 64));
            float p = valid ? __expf(eij - m) : 0.f;
            float s = p;
#pragma unroll
            for (int off = 32; off > 0; off >>= 1)
                s += __shfl_xor(s, off, 64);
            const float inv_s = 1.0f / s;

            for (int k = 0; k < d; ++k) {
                const float a = __shfl(p, k, 64) * inv_s;
                const int   j = __shfl(nbr, k, 64);
                const float4* src = (j < id) ? (o4r + (size_t)j * D4)
                                             : (f4  + (size_t)j * D4);
                float4 v0 = src[lane];
                float4 v1 = src[lane + 64];
                acc0.x += a * v0.x; acc0.y += a * v0.y;
                acc0.z += a * v0.z; acc0.w += a * v0.w;
                acc1.x += a * v1.x; acc1.y += a * v1.y;
                acc1.z += a * v1.z; acc1.w += a * v1.w;
            }
        }

        const float4 c0 = f4[(size_t)id * D4 + lane];
        const float4 c1 = f4[(size_t)id * D4 + lane + 64];
        float4 g0 = {c0.x + acc0.x, c0.y + acc0.y, c0.z + acc0.z, c0.w + acc0.w};
        float4 g1 = {c1.x + acc1.x, c1.y + acc1.y, c1.z + acc1.z, c1.w + acc1.w};
        float4* orow = (float4*)out + (size_t)id * D4;
        orow[lane]      = g0;
        orow[lane + 64] = g1;

        // ej_new[id] = g . wk + bk  (consumers then never redo neighbor dots)
        float4 w0 = wk4[lane], w1 = wk4[lane + 64];
        float pd = g0.x * w0.x + g0.y * w0.y + g0.z * w0.z + g0.w * w0.w
                 + g1.x * w1.x + g1.y * w1.y + g1.z * w1.z + g1.w * w1.w;
#pragma unroll
        for (int off = 32; off > 0; off >>= 1)
            pd += __shfl_xor(pd, off, 64);
        if (lane == 0) ej_new[id] = pd + wkb;

        // Release: flush row + ej_new device-wide (wbl2), then publish flag.
        __threadfence();
        if (lane == 0)
            __hip_atomic_store(&flags[id], 1, __ATOMIC_RELEASE,
                               __HIP_MEMORY_SCOPE_AGENT);
    }
}

extern "C" void kernel_launch(void* const* d_in, const int* in_sizes, int n_in,
                              void* d_out, int out_size, void* d_ws, size_t ws_size,
                              hipStream_t stream)
{
    const float* feats     = (const float*)d_in[0];
    const float* wq_w      = (const float*)d_in[1];
    const float* wq_b      = (const float*)d_in[2];
    const float* wk_w      = (const float*)d_in[3];
    const float* wk_b      = (const float*)d_in[4];
    const int*   neighbors = (const int*)d_in[5];
    const int*   deg       = (const int*)d_in[6];
    float*       out       = (float*)d_out;

    // Workspace layout: [flags: NN ints][counter + pad: 16 ints][ei: NN f][ej_orig: NN f][ej_new: NN f]
    char*  ws      = (char*)d_ws;
    int*   flags   = (int*)ws;
    int*   counter = flags + NN;
    float* ei      = (float*)(ws + (size_t)(NN + 16) * sizeof(int));
    float* ej_orig = ei + NN;
    float* ej_new  = ej_orig + NN;

    hipMemsetAsync(d_ws, 0, (size_t)(NN + 16) * sizeof(int), stream);

    // One wave per node: NN waves, 4 waves per 256-thread block.
    dim3 pb(256), pg((NN + 3) / 4);
    precomp_kernel<<<pg, pb, 0, stream>>>(feats, wq_w, wq_b, wk_w, wk_b, ei, ej_orig);

    // Persistent dataflow workers: 512 blocks x 4 waves = 2048 workers.
    attn_dataflow<<<dim3(512), dim3(256), 0, stream>>>(
        feats, wk_w, wk_b, neighbors, deg, ei, ej_orig, ej_new, flags, counter, out);
}

// Round 3
// 842.384 us; speedup vs baseline: 11.7564x; 11.7564x over previous
//
#include <hip/hip_runtime.h>

// Graph-attention sequential sweep as dataflow over the dependency DAG.
// Node i depends only on out-rows g[j] for j in neighbors[i], j<i, k<deg[i].
// Workers grab node ids IN ORDER via atomic counter (deadlock-free: the
// smallest unfinished id is always held by a resident wave whose deps are
// all finished, so it can always make progress).
//
// Coherence scheme (NO buffer_inv / NO buffer_wbl2 anywhere):
//  - producer: out-row stores write-through to LLC (sc0 sc1), ej_new + flag
//    via relaxed agent atomics (sc1), ordered by an explicit s_waitcnt.
//  - consumer: polls flags with relaxed agent loads (sc1, no L2 invalidate);
//    reads ej_new with relaxed agent loads (its lines are shared across
//    nodes); reads out-rows with NORMAL cached loads — safe because each
//    2KB row occupies exclusive cachelines and is first read only after its
//    flag is set, so no stale copy can exist in any cache.

constexpr int NN = 50000;
constexpr int D  = 512;
constexpr int K  = 32;
constexpr int D4 = D / 4; // 128 float4 per row

typedef float v4f __attribute__((ext_vector_type(4)));

__device__ __forceinline__ void store_f4_llc(float* p, float4 v) {
    // write-through to the memory-side Infinity Cache (device coherence point)
    v4f vv; vv.x = v.x; vv.y = v.y; vv.z = v.z; vv.w = v.w;
    asm volatile("global_store_dwordx4 %0, %1, off sc0 sc1"
                 :: "v"(p), "v"(vv) : "memory");
}

__global__ __launch_bounds__(256) void precomp_kernel(
    const float* __restrict__ feats,
    const float* __restrict__ wq_w, const float* __restrict__ wq_b,
    const float* __restrict__ wk_w, const float* __restrict__ wk_b,
    float* __restrict__ ei, float* __restrict__ ej_orig)
{
    int gw   = (int)((blockIdx.x * blockDim.x + threadIdx.x) >> 6); // global wave id
    int lane = threadIdx.x & 63;
    if (gw >= NN) return;
    const float4* row = (const float4*)feats + (size_t)gw * D4;
    const float4* q4  = (const float4*)wq_w;
    const float4* k4  = (const float4*)wk_w;
    float dq = 0.f, dk = 0.f;
#pragma unroll
    for (int c = 0; c < 2; ++c) {
        float4 v  = row[lane + 64 * c];
        float4 q  = q4[lane + 64 * c];
        float4 kk = k4[lane + 64 * c];
        dq += v.x * q.x + v.y * q.y + v.z * q.z + v.w * q.w;
        dk += v.x * kk.x + v.y * kk.y + v.z * kk.z + v.w * kk.w;
    }
#pragma unroll
    for (int off = 32; off > 0; off >>= 1) {
        dq += __shfl_down(dq, off, 64);
        dk += __shfl_down(dk, off, 64);
    }
    if (lane == 0) {
        ei[gw]      = dq + wq_b[0];
        ej_orig[gw] = dk + wk_b[0];
    }
}

__global__ __launch_bounds__(256) void attn_dataflow(
    const float* __restrict__ feats,
    const int* __restrict__ neighbors, const int* __restrict__ deg,
    const float* __restrict__ ei_arr, const float* __restrict__ ej_orig,
    const float* __restrict__ wk_w, const float* __restrict__ wk_b,
    int* ej_new, int* flags, int* counter,
    float* out)
{
    const int lane = threadIdx.x & 63;
    const float4* f4  = (const float4*)feats;
    const float4* o4r = (const float4*)out;
    const float4* wk4 = (const float4*)wk_w;
    const float   wkb = wk_b[0];

    for (;;) {
        int id = 0;
        if (lane == 0) id = atomicAdd(counter, 1);
        id = __shfl(id, 0, 64);
        if (id >= NN) return;

        // ---- everything independent of deps, loaded BEFORE the wait ----
        const int d = deg[id];
        int nbr = 0;
        if (lane < K) nbr = neighbors[(size_t)id * K + lane];
        const bool valid = lane < d;                 // d <= 32, lanes>=32 never valid
        const bool isdep = valid && (nbr < id);

        const float4 c0 = f4[(size_t)id * D4 + lane];
        const float4 c1 = f4[(size_t)id * D4 + lane + 64];
        const float eii = ei_arr[id];
        float ej = 0.f;
        if (valid && !isdep) ej = ej_orig[nbr];

        // ---- wait for updated neighbors: relaxed sc1 polls, NO cache inv ----
        if (isdep) {
            while (__hip_atomic_load(&flags[nbr], __ATOMIC_RELAXED,
                                     __HIP_MEMORY_SCOPE_AGENT) == 0) {
                __builtin_amdgcn_s_sleep(1);
            }
            ej = __int_as_float(__hip_atomic_load(&ej_new[nbr], __ATOMIC_RELAXED,
                                                  __HIP_MEMORY_SCOPE_AGENT));
        }

        float4 acc0 = {0.f, 0.f, 0.f, 0.f};
        float4 acc1 = {0.f, 0.f, 0.f, 0.f};

        if (d > 0) {
            float eij = valid ? eii * ej : -3.0e38f;
            float m = eij;
#pragma unroll
            for (int off = 32; off > 0; off >>= 1)
                m = fmaxf(m, __shfl_xor(m, off, 64));
            float p = valid ? __expf(eij - m) : 0.f;
            float s = p;
#pragma unroll
            for (int off = 32; off > 0; off >>= 1)
                s += __shfl_xor(s, off, 64);
            const float inv_s = 1.0f / s;

            for (int k = 0; k < d; ++k) {
                const float a = __shfl(p, k, 64) * inv_s;
                const int   j = __shfl(nbr, k, 64);
                const float4* src = (j < id) ? (o4r + (size_t)j * D4)
                                             : (f4  + (size_t)j * D4);
                float4 v0 = src[lane];
                float4 v1 = src[lane + 64];
                acc0.x += a * v0.x; acc0.y += a * v0.y;
                acc0.z += a * v0.z; acc0.w += a * v0.w;
                acc1.x += a * v1.x; acc1.y += a * v1.y;
                acc1.z += a * v1.z; acc1.w += a * v1.w;
            }
        }

        float4 g0 = {c0.x + acc0.x, c0.y + acc0.y, c0.z + acc0.z, c0.w + acc0.w};
        float4 g1 = {c1.x + acc1.x, c1.y + acc1.y, c1.z + acc1.z, c1.w + acc1.w};
        float* orow = out + (size_t)id * D;
        store_f4_llc(orow + 4 * lane,        g0);
        store_f4_llc(orow + 4 * (lane + 64), g1);

        // ej_new[id] = g . wk + bk
        float4 w0 = wk4[lane], w1 = wk4[lane + 64];
        float pd = g0.x * w0.x + g0.y * w0.y + g0.z * w0.z + g0.w * w0.w
                 + g1.x * w1.x + g1.y * w1.y + g1.z * w1.z + g1.w * w1.w;
#pragma unroll
        for (int off = 32; off > 0; off >>= 1)
            pd += __shfl_xor(pd, off, 64);
        if (lane == 0)
            __hip_atomic_store(&ej_new[id], __float_as_int(pd + wkb),
                               __ATOMIC_RELAXED, __HIP_MEMORY_SCOPE_AGENT);

        // order payload (row + ej_new, all at LLC) before the flag; no wbl2
        __builtin_amdgcn_s_waitcnt(0);
        if (lane == 0)
            __hip_atomic_store(&flags[id], 1, __ATOMIC_RELAXED,
                               __HIP_MEMORY_SCOPE_AGENT);
    }
}

extern "C" void kernel_launch(void* const* d_in, const int* in_sizes, int n_in,
                              void* d_out, int out_size, void* d_ws, size_t ws_size,
                              hipStream_t stream)
{
    const float* feats     = (const float*)d_in[0];
    const float* wq_w      = (const float*)d_in[1];
    const float* wq_b      = (const float*)d_in[2];
    const float* wk_w      = (const float*)d_in[3];
    const float* wk_b      = (const float*)d_in[4];
    const int*   neighbors = (const int*)d_in[5];
    const int*   deg       = (const int*)d_in[6];
    float*       out       = (float*)d_out;

    // ws: [flags: NN][pad][counter][pad][ei: NN f][ej_orig: NN f][ej_new: NN i]
    char*  ws      = (char*)d_ws;
    int*   flags   = (int*)ws;
    int*   counter = flags + NN + 64;               // own cacheline
    float* ei      = (float*)(ws + (size_t)(NN + 128) * sizeof(int));
    float* ej_orig = ei + NN;
    int*   ej_new  = (int*)(ej_orig + NN);

    (void)hipMemsetAsync(d_ws, 0, (size_t)(NN + 128) * sizeof(int), stream);

    dim3 pb(256), pg((NN + 3) / 4);
    precomp_kernel<<<pg, pb, 0, stream>>>(feats, wq_w, wq_b, wk_w, wk_b, ei, ej_orig);

    attn_dataflow<<<dim3(512), dim3(256), 0, stream>>>(
        feats, neighbors, deg, ei, ej_orig, wk_w, wk_b, ej_new, flags, counter, out);
}